// Round 3
// baseline (631.456 us; speedup 1.0000x reference)
//
#include <hip/hip_runtime.h>
#include <math.h>

#define BB 2
#define TT 128
#define NN 64
#define DD 128
#define HH 8
#define DKK 16
#define DEE 32
#define LWW 8
#define BNN (BB*NN)   // 128
#define SCP 132       // padded sc row stride (bank rotation)
#define ROWS 4        // t rows per attn block

typedef float floatx4 __attribute__((ext_vector_type(4)));

// ---------------- Kernel 1: QKV GEMM (16384x128 @ 128x384) ----------------
// Grid 1024 blocks x 256 threads; 16 rows/block; LDS 32KB.
// Outputs: Q[bn][t][h*16+dk], K[bn][h][s][dk], V[bn][h][dk][s]
__global__ __launch_bounds__(256) void qkv_kernel(
    const float* __restrict__ node, const float* __restrict__ Wqkv,
    const float* __restrict__ bqkv,
    float* __restrict__ Q, float* __restrict__ K, float* __restrict__ V) {
  __shared__ float xs[16 * 128];     // 8 KB
  __shared__ float wl[16 * 384];     // 24 KB
  const int tid = threadIdx.x;
  const int row0 = blockIdx.x * 16;

  // load x tile: x[bn,t,d] = node[b,t,n,d]
  for (int i4 = tid; i4 < 512; i4 += 256) {
    int r = i4 >> 5, d4 = i4 & 31;
    int rowg = row0 + r;
    int bn = rowg >> 7, t = rowg & 127;
    int b = bn >> 6, n = bn & 63;
    *(float4*)&xs[r * 128 + d4 * 4] =
        *(const float4*)&node[(((size_t)(b * TT + t)) * NN + n) * DD + d4 * 4];
  }

  float acc[24];
#pragma unroll
  for (int i = 0; i < 24; ++i) acc[i] = 0.f;
  const int tr = tid >> 5;   // 0..7  -> rows tr*2, tr*2+1
  const int tc = tid & 31;   // 0..31 -> cols tc*12 .. tc*12+11

  for (int ct = 0; ct < 8; ++ct) {
    __syncthreads();
    for (int i4 = tid; i4 < 1536; i4 += 256) {  // 16x384 floats = 1536 float4
      int c = i4 / 96, j4 = i4 % 96;
      *(float4*)&wl[c * 384 + j4 * 4] =
          *(const float4*)&Wqkv[(size_t)(ct * 16 + c) * 384 + j4 * 4];
    }
    __syncthreads();
#pragma unroll
    for (int cl4 = 0; cl4 < 4; ++cl4) {
      floatx4 xr[2];
#pragma unroll
      for (int i = 0; i < 2; ++i)
        xr[i] = *(const floatx4*)&xs[(tr * 2 + i) * 128 + ct * 16 + cl4 * 4];
#pragma unroll
      for (int jj = 0; jj < 4; ++jj) {
        const float* wp = &wl[(cl4 * 4 + jj) * 384 + tc * 12];
        floatx4 w0 = *(const floatx4*)&wp[0];
        floatx4 w1 = *(const floatx4*)&wp[4];
        floatx4 w2 = *(const floatx4*)&wp[8];
#pragma unroll
        for (int i = 0; i < 2; ++i) {
          float x = xr[i][jj];
          acc[i * 12 + 0] += x * w0[0];  acc[i * 12 + 1] += x * w0[1];
          acc[i * 12 + 2] += x * w0[2];  acc[i * 12 + 3] += x * w0[3];
          acc[i * 12 + 4] += x * w1[0];  acc[i * 12 + 5] += x * w1[1];
          acc[i * 12 + 6] += x * w1[2];  acc[i * 12 + 7] += x * w1[3];
          acc[i * 12 + 8] += x * w2[0];  acc[i * 12 + 9] += x * w2[1];
          acc[i * 12 +10] += x * w2[2];  acc[i * 12 +11] += x * w2[3];
        }
      }
    }
  }

  // epilogue: cols tc*12..+11 lie within one h block (48 cols); j = h*48+dk*3+c
  const int h = tc >> 2;
  const int dk0 = (tc & 3) * 4;
#pragma unroll
  for (int i = 0; i < 2; ++i) {
    int rowg = row0 + tr * 2 + i;
    int bn = rowg >> 7, t = rowg & 127;
    float qv[4], kv[4], vv[4];
#pragma unroll
    for (int dl = 0; dl < 4; ++dl) {
      int jb = h * 48 + (dk0 + dl) * 3;
      qv[dl] = acc[i * 12 + dl * 3 + 0] + bqkv[jb + 0];
      kv[dl] = acc[i * 12 + dl * 3 + 1] + bqkv[jb + 1];
      vv[dl] = acc[i * 12 + dl * 3 + 2] + bqkv[jb + 2];
    }
    *(float4*)&Q[(size_t)rowg * 128 + h * 16 + dk0] = *(float4*)qv;
    *(float4*)&K[(((size_t)(bn * 8 + h)) * 128 + t) * 16 + dk0] = *(float4*)kv;
#pragma unroll
    for (int dl = 0; dl < 4; ++dl)
      V[(((size_t)(bn * 8 + h)) * 16 + dk0 + dl) * 128 + t] = vv[dl];
  }
}

// ---------------- Kernel 2: fused attention + edge update ----------------
// One block = (bn, 4 t rows); wave w owns row t0+w. 4096 blocks x 256 thr.
// LDS ~18.5 KB -> 8 blocks/CU (occupancy lever). ONE __syncthreads; all
// later phases wave-local -> waves slip freely and hide VMEM latency.
__global__ __launch_bounds__(256) void attn_kernel(
    const float* __restrict__ Q, const float* __restrict__ K,
    const float* __restrict__ V, const float* __restrict__ tv,
    const int* __restrict__ mask,
    const float* __restrict__ Wg, const float* __restrict__ bg,
    const float* __restrict__ Wout, const float* __restrict__ bout,
    const float* __restrict__ Wupd, const float* __restrict__ bupd,
    float* __restrict__ out0, float* __restrict__ out1) {
  __shared__ float sc[32 * SCP];     // [(r*8+h)*SCP + s], 16.5 KB
  __shared__ float xo[4][128];       // per-wave xo row, 2 KB

  const int tid = threadIdx.x;
  // XCD-locality swizzle: same bn -> same (blockIdx%8) class
  const int xcd = blockIdx.x & 7;
  const int i = blockIdx.x >> 3;          // 0..511
  const int bn = xcd * 16 + (i & 15);     // 0..127
  const int t0 = (i >> 4) * ROWS;         // 0..124
  const int b = bn >> 6, n = bn & 63;

  // ---- Phase A (cross-wave): scores = q.k/4 for the 4 rows ----
  {
    const int h = tid >> 5;        // 0..7
    const int s4 = tid & 31;       // s = s4*4 .. +3
    const floatx4* kp =
        (const floatx4*)&K[(((size_t)(bn * 8 + h)) * 128 + s4 * 4) * 16];
    floatx4 kr[16];
#pragma unroll
    for (int u = 0; u < 16; ++u) kr[u] = kp[u];
    int4 mi = *(const int4*)&mask[b * TT + s4 * 4];
    int m[4] = {mi.x, mi.y, mi.z, mi.w};
#pragma unroll
    for (int t8 = 0; t8 < ROWS; ++t8) {
      const floatx4* qp =
          (const floatx4*)&Q[((size_t)(bn * TT + t0 + t8)) * 128 + h * 16];
      floatx4 q0 = qp[0], q1 = qp[1], q2 = qp[2], q3 = qp[3];
      const int t = t0 + t8;
      floatx4 res;
#pragma unroll
      for (int j = 0; j < 4; ++j) {
        floatx4 p = q0 * kr[j * 4 + 0];
        p += q1 * kr[j * 4 + 1];
        p += q2 * kr[j * 4 + 2];
        p += q3 * kr[j * 4 + 3];
        float v = (p[0] + p[1] + p[2] + p[3]) * 0.25f;
        int s = s4 * 4 + j;
        bool inband = (s >= t - LWW) && (s <= t + LWW);
        if (!inband) {
          v = fminf(fmaxf(v, -5.f), 5.f);
          if (m[j] == 0) v = 1e-28f;
        }
        res[j] = v;
      }
      *(floatx4*)&sc[(t8 * 8 + h) * SCP + s4 * 4] = res;
    }
  }
  __syncthreads();  // the only block-wide barrier

  const int wid = tid >> 6, lane = tid & 63;
  const int tw = t0 + wid;                 // this wave's row
  float* scw = &sc[wid * 8 * SCP];         // wave's sc slice: [h*SCP + s]

  // ---- Phase B (wave-local): banded edge bias g = tv@Wg+bg; clip+mask ----
  if (lane < 2 * LWW + 1) {
    const int s = tw - LWW + lane;
    if (s >= 0 && s < TT) {
      const floatx4* tp =
          (const floatx4*)&tv[(((size_t)(bn * TT + tw)) * TT + s) * DEE];
      floatx4 glo = *(const floatx4*)&bg[0];
      floatx4 ghi = *(const floatx4*)&bg[4];
#pragma unroll
      for (int c4 = 0; c4 < 8; ++c4) {
        floatx4 tvv = tp[c4];
#pragma unroll
        for (int k = 0; k < 4; ++k) {
          floatx4 wlo = *(const floatx4*)&Wg[(c4 * 4 + k) * 8];
          floatx4 whi = *(const floatx4*)&Wg[(c4 * 4 + k) * 8 + 4];
          glo += tvv[k] * wlo;
          ghi += tvv[k] * whi;
        }
      }
      int m0 = mask[b * TT + s];
      float* base = &scw[s];
#pragma unroll
      for (int h = 0; h < 8; ++h) {
        float gv = (h < 4) ? glo[h] : ghi[h - 4];
        float v = base[h * SCP] + gv;
        v = fminf(fmaxf(v, -5.f), 5.f);
        if (m0 == 0) v = 1e-28f;
        base[h * SCP] = v;
      }
    }
  }
  __builtin_amdgcn_wave_barrier();

  // ---- Phase C (wave-local): tv_out = sc @ W_upd + b_upd, NT stores ----
  {
    const int e4 = lane & 7;    // output float4 within DE
    const int sq0 = lane >> 3;  // s-quads sq0, sq0+8, sq0+16, sq0+24
    floatx4 wv[HH];
#pragma unroll
    for (int h = 0; h < HH; ++h) wv[h] = *(const floatx4*)&Wupd[h * 32 + e4 * 4];
    floatx4 bu = *(const floatx4*)&bupd[e4 * 4];
    float* op = out1 + ((size_t)(bn * TT + tw)) * TT * DEE;
#pragma unroll
    for (int si = 0; si < 4; ++si) {
      int sq = sq0 + si * 8;
      floatx4 o0 = bu, o1 = bu, o2 = bu, o3 = bu;
#pragma unroll
      for (int h = 0; h < HH; ++h) {
        floatx4 f = *(const floatx4*)&scw[h * SCP + sq * 4];
        o0 += f[0] * wv[h];
        o1 += f[1] * wv[h];
        o2 += f[2] * wv[h];
        o3 += f[3] * wv[h];
      }
      __builtin_nontemporal_store(o0, (floatx4*)&op[(sq * 4 + 0) * DEE + e4 * 4]);
      __builtin_nontemporal_store(o1, (floatx4*)&op[(sq * 4 + 1) * DEE + e4 * 4]);
      __builtin_nontemporal_store(o2, (floatx4*)&op[(sq * 4 + 2) * DEE + e4 * 4]);
      __builtin_nontemporal_store(o3, (floatx4*)&op[(sq * 4 + 3) * DEE + e4 * 4]);
    }
  }
  __builtin_amdgcn_wave_barrier();

  // ---- Phase D (wave-local): softmax over s per h; 8 lanes per h ----
  {
    const int h = lane >> 3, sp = lane & 7;  // lane's s set: sp*4+{0..3}+32q
    int4 mi0 = *(const int4*)&mask[b * TT + sp * 4];
    int4 mi1 = *(const int4*)&mask[b * TT + sp * 4 + 32];
    int4 mi2 = *(const int4*)&mask[b * TT + sp * 4 + 64];
    int4 mi3 = *(const int4*)&mask[b * TT + sp * 4 + 96];
    float* rp = &scw[h * SCP];
    floatx4 x0 = *(const floatx4*)&rp[sp * 4];
    floatx4 x1 = *(const floatx4*)&rp[sp * 4 + 32];
    floatx4 x2 = *(const floatx4*)&rp[sp * 4 + 64];
    floatx4 x3 = *(const floatx4*)&rp[sp * 4 + 96];
    float m = fmaxf(fmaxf(fmaxf(x0[0], x0[1]), fmaxf(x0[2], x0[3])),
                    fmaxf(fmaxf(x1[0], x1[1]), fmaxf(x1[2], x1[3])));
    m = fmaxf(m, fmaxf(fmaxf(fmaxf(x2[0], x2[1]), fmaxf(x2[2], x2[3])),
                       fmaxf(fmaxf(x3[0], x3[1]), fmaxf(x3[2], x3[3]))));
    m = fmaxf(m, __shfl_xor(m, 1));
    m = fmaxf(m, __shfl_xor(m, 2));
    m = fmaxf(m, __shfl_xor(m, 4));
    floatx4 e0, e1, e2, e3;
#pragma unroll
    for (int j = 0; j < 4; ++j) {
      e0[j] = __expf(x0[j] - m);
      e1[j] = __expf(x1[j] - m);
      e2[j] = __expf(x2[j] - m);
      e3[j] = __expf(x3[j] - m);
    }
    float ssum = (e0[0] + e0[1] + e0[2] + e0[3]) + (e1[0] + e1[1] + e1[2] + e1[3]) +
                 (e2[0] + e2[1] + e2[2] + e2[3]) + (e3[0] + e3[1] + e3[2] + e3[3]);
    ssum += __shfl_xor(ssum, 1);
    ssum += __shfl_xor(ssum, 2);
    ssum += __shfl_xor(ssum, 4);
    float inv = 1.f / ssum;
    floatx4 y0, y1, y2, y3;
    y0[0] = (mi0.x == 0) ? 0.f : e0[0] * inv;
    y0[1] = (mi0.y == 0) ? 0.f : e0[1] * inv;
    y0[2] = (mi0.z == 0) ? 0.f : e0[2] * inv;
    y0[3] = (mi0.w == 0) ? 0.f : e0[3] * inv;
    y1[0] = (mi1.x == 0) ? 0.f : e1[0] * inv;
    y1[1] = (mi1.y == 0) ? 0.f : e1[1] * inv;
    y1[2] = (mi1.z == 0) ? 0.f : e1[2] * inv;
    y1[3] = (mi1.w == 0) ? 0.f : e1[3] * inv;
    y2[0] = (mi2.x == 0) ? 0.f : e2[0] * inv;
    y2[1] = (mi2.y == 0) ? 0.f : e2[1] * inv;
    y2[2] = (mi2.z == 0) ? 0.f : e2[2] * inv;
    y2[3] = (mi2.w == 0) ? 0.f : e2[3] * inv;
    y3[0] = (mi3.x == 0) ? 0.f : e3[0] * inv;
    y3[1] = (mi3.y == 0) ? 0.f : e3[1] * inv;
    y3[2] = (mi3.z == 0) ? 0.f : e3[2] * inv;
    y3[3] = (mi3.w == 0) ? 0.f : e3[3] * inv;
    *(floatx4*)&rp[sp * 4]      = y0;
    *(floatx4*)&rp[sp * 4 + 32] = y1;
    *(floatx4*)&rp[sp * 4 + 64] = y2;
    *(floatx4*)&rp[sp * 4 + 96] = y3;
  }
  __builtin_amdgcn_wave_barrier();

  // ---- Phase E (wave-local): xo = attn @ V; lane = (h, dk2) ----
  {
    const int h = lane >> 3, dk2 = lane & 7;
    const floatx4* vp0 =
        (const floatx4*)&V[(((size_t)(bn * 8 + h)) * 16 + dk2) * 128];
    const floatx4* vp1 =
        (const floatx4*)&V[(((size_t)(bn * 8 + h)) * 16 + dk2 + 8) * 128];
    const floatx4* ap = (const floatx4*)&scw[h * SCP];
    floatx4 a0 = 0.f, a1 = 0.f;
#pragma unroll 8
    for (int s4 = 0; s4 < 32; ++s4) {
      floatx4 p = ap[s4];
      a0 += p * vp0[s4];
      a1 += p * vp1[s4];
    }
    xo[wid][h * 16 + dk2]     = a0[0] + a0[1] + a0[2] + a0[3];
    xo[wid][h * 16 + dk2 + 8] = a1[0] + a1[1] + a1[2] + a1[3];
  }
  __builtin_amdgcn_wave_barrier();

  // ---- Phase F (wave-local): out0 row = xo @ W_out + b_out; c split
  //      across wave halves, combined via shfl_xor(.,32) ----
  {
    const int d4 = lane & 31, ch = lane >> 5;
    const float* xp = &xo[wid][0];
    floatx4 acc = 0.f;
#pragma unroll 8
    for (int ci = 0; ci < 64; ++ci) {
      int c = ch * 64 + ci;
      floatx4 w = *(const floatx4*)&Wout[(size_t)c * 128 + d4 * 4];
      acc += xp[c] * w;
    }
#pragma unroll
    for (int j = 0; j < 4; ++j) acc[j] += __shfl_xor(acc[j], 32);
    if (ch == 0) {
      floatx4 bo = *(const floatx4*)&bout[d4 * 4];
      floatx4 res = acc + bo;
      __builtin_nontemporal_store(res,
          (floatx4*)&out0[(((size_t)(b * TT + tw)) * NN + n) * DD + d4 * 4]);
    }
  }
}

extern "C" void kernel_launch(void* const* d_in, const int* in_sizes, int n_in,
                              void* d_out, int out_size, void* d_ws, size_t ws_size,
                              hipStream_t stream) {
  const float* node = (const float*)d_in[0];
  const float* tv   = (const float*)d_in[1];
  const int*   mask = (const int*)d_in[2];
  // d_in[3] local_mask: banded |i-j|<=LW, synthesized in-kernel
  const float* Wqkv = (const float*)d_in[4];
  const float* bqkv = (const float*)d_in[5];
  const float* Wg   = (const float*)d_in[6];
  const float* bg   = (const float*)d_in[7];
  const float* Wout = (const float*)d_in[8];
  const float* bout = (const float*)d_in[9];
  const float* Wupd = (const float*)d_in[10];
  const float* bupd = (const float*)d_in[11];

  float* out0 = (float*)d_out;                       // (B,T,N,D)
  float* out1 = out0 + (size_t)BB * TT * NN * DD;    // (B,N,T,T,DE)

  float* Q = (float*)d_ws;                           // BN*T*128 each
  float* K = Q + (size_t)BNN * TT * DD;
  float* V = K + (size_t)BNN * TT * DD;

  qkv_kernel<<<1024, 256, 0, stream>>>(node, Wqkv, bqkv, Q, K, V);
  attn_kernel<<<4096, 256, 0, stream>>>(Q, K, V, tv, mask, Wg, bg, Wout, bout,
                                        Wupd, bupd, out0, out1);
}

// Round 4
// 548.548 us; speedup vs baseline: 1.1511x; 1.1511x over previous
//
#include <hip/hip_runtime.h>
#include <math.h>

#define BB 2
#define TT 128
#define NN 64
#define DD 128
#define HH 8
#define DKK 16
#define DEE 32
#define LWW 8
#define BNN (BB*NN)   // 128
#define SCP 132       // padded sc row stride (bank rotation)

typedef float floatx4 __attribute__((ext_vector_type(4)));

// ---------------- Kernel 1: QKV GEMM (16384x128 @ 128x384) ----------------
// 256 blocks x 256 threads, 64 rows/block (one block per CU, single round).
// Wqkv re-read = 256 x 192KB = 49MB L2 (was 197MB); 16 barriers amortize
// over 4x the FLOPs. 96 acc/thread; launch_bounds(256,1) -> VGPR headroom.
// Outputs: Q[bn][t][h*16+dk], K[bn][h][s][dk], V[bn][h][dk][s]
__global__ __launch_bounds__(256, 1) void qkv_kernel(
    const float* __restrict__ node, const float* __restrict__ Wqkv,
    const float* __restrict__ bqkv,
    float* __restrict__ Q, float* __restrict__ K, float* __restrict__ V) {
  __shared__ float xs[64 * 128];     // 32 KB
  __shared__ float wl[16 * 384];     // 24 KB
  const int tid = threadIdx.x;
  const int row0 = blockIdx.x * 64;

  // load x tile: x[bn,t,d] = node[b,t,n,d]
  for (int i4 = tid; i4 < 2048; i4 += 256) {
    int r = i4 >> 5, d4 = i4 & 31;
    int rowg = row0 + r;
    int bn = rowg >> 7, t = rowg & 127;
    int b = bn >> 6, n = bn & 63;
    *(float4*)&xs[r * 128 + d4 * 4] =
        *(const float4*)&node[(((size_t)(b * TT + t)) * NN + n) * DD + d4 * 4];
  }

  float acc[96];
#pragma unroll
  for (int i = 0; i < 96; ++i) acc[i] = 0.f;
  const int tr = tid >> 5;   // 0..7  -> rows tr*8 .. tr*8+7
  const int tc = tid & 31;   // 0..31 -> cols tc*12 .. tc*12+11

  for (int ct = 0; ct < 8; ++ct) {
    __syncthreads();
    for (int i4 = tid; i4 < 1536; i4 += 256) {  // 16x384 floats = 1536 float4
      int c = i4 / 96, j4 = i4 % 96;
      *(float4*)&wl[c * 384 + j4 * 4] =
          *(const float4*)&Wqkv[(size_t)(ct * 16 + c) * 384 + j4 * 4];
    }
    __syncthreads();
#pragma unroll
    for (int cl4 = 0; cl4 < 4; ++cl4) {
      floatx4 xr[8];
#pragma unroll
      for (int i = 0; i < 8; ++i)
        xr[i] = *(const floatx4*)&xs[(tr * 8 + i) * 128 + ct * 16 + cl4 * 4];
#pragma unroll
      for (int jj = 0; jj < 4; ++jj) {
        const float* wp = &wl[(cl4 * 4 + jj) * 384 + tc * 12];
        floatx4 w0 = *(const floatx4*)&wp[0];
        floatx4 w1 = *(const floatx4*)&wp[4];
        floatx4 w2 = *(const floatx4*)&wp[8];
#pragma unroll
        for (int i = 0; i < 8; ++i) {
          float x = xr[i][jj];
          acc[i * 12 + 0] += x * w0[0];  acc[i * 12 + 1] += x * w0[1];
          acc[i * 12 + 2] += x * w0[2];  acc[i * 12 + 3] += x * w0[3];
          acc[i * 12 + 4] += x * w1[0];  acc[i * 12 + 5] += x * w1[1];
          acc[i * 12 + 6] += x * w1[2];  acc[i * 12 + 7] += x * w1[3];
          acc[i * 12 + 8] += x * w2[0];  acc[i * 12 + 9] += x * w2[1];
          acc[i * 12 +10] += x * w2[2];  acc[i * 12 +11] += x * w2[3];
        }
      }
    }
  }

  // epilogue: cols tc*12..+11 lie within one h block (48 cols); j = h*48+dk*3+c
  const int h = tc >> 2;
  const int dk0 = (tc & 3) * 4;
#pragma unroll
  for (int i = 0; i < 8; ++i) {
    int rowg = row0 + tr * 8 + i;
    int bn = rowg >> 7, t = rowg & 127;
    float qv[4], kv[4], vv[4];
#pragma unroll
    for (int dl = 0; dl < 4; ++dl) {
      int jb = h * 48 + (dk0 + dl) * 3;
      qv[dl] = acc[i * 12 + dl * 3 + 0] + bqkv[jb + 0];
      kv[dl] = acc[i * 12 + dl * 3 + 1] + bqkv[jb + 1];
      vv[dl] = acc[i * 12 + dl * 3 + 2] + bqkv[jb + 2];
    }
    *(float4*)&Q[(size_t)rowg * 128 + h * 16 + dk0] = *(float4*)qv;
    *(float4*)&K[(((size_t)(bn * 8 + h)) * 128 + t) * 16 + dk0] = *(float4*)kv;
#pragma unroll
    for (int dl = 0; dl < 4; ++dl)
      V[(((size_t)(bn * 8 + h)) * 16 + dk0 + dl) * 128 + t] = vv[dl];
  }
}

// ---------------- Kernel 2: fused attention + edge update ----------------
// One block = (bn, 8 t rows); wave w owns rows t0+2w, t0+2w+1.  (R2 winner:
// 2-row/wave amortization of K/V/Wout beats nominal occupancy headroom.)
// Exactly ONE __syncthreads (after cross-wave scores); all later phases are
// wave-local on the wave's own sc slice -> waves slip freely (latency hiding).
__global__ __launch_bounds__(256) void attn_kernel(
    const float* __restrict__ Q, const float* __restrict__ K,
    const float* __restrict__ V, const float* __restrict__ tv,
    const int* __restrict__ mask,
    const float* __restrict__ Wg, const float* __restrict__ bg,
    const float* __restrict__ Wout, const float* __restrict__ bout,
    const float* __restrict__ Wupd, const float* __restrict__ bupd,
    float* __restrict__ out0, float* __restrict__ out1) {
  __shared__ float sc[64 * SCP];     // [(t8*8+h)*SCP + s], 33 KB, bank-rotated
  __shared__ float xo[4][2][128];    // per-wave xo rows, 4 KB

  const int tid = threadIdx.x;
  // XCD-locality swizzle: same bn -> same (blockIdx%8) class
  const int xcd = blockIdx.x & 7;
  const int i = blockIdx.x >> 3;          // 0..255
  const int bn = xcd * 16 + (i & 15);     // 0..127
  const int t0 = (i >> 4) * 8;            // 0..120
  const int b = bn >> 6, n = bn & 63;

  // ---- Phase A (cross-wave): scores = q.k/4 for all 8 rows ----
  {
    const int h = tid >> 5;        // 0..7
    const int s4 = tid & 31;       // s = s4*4 .. +3
    const floatx4* kp =
        (const floatx4*)&K[(((size_t)(bn * 8 + h)) * 128 + s4 * 4) * 16];
    floatx4 kr[16];
#pragma unroll
    for (int u = 0; u < 16; ++u) kr[u] = kp[u];
    int4 mi = *(const int4*)&mask[b * TT + s4 * 4];
    int m[4] = {mi.x, mi.y, mi.z, mi.w};
#pragma unroll
    for (int t8 = 0; t8 < 8; ++t8) {
      const floatx4* qp =
          (const floatx4*)&Q[((size_t)(bn * TT + t0 + t8)) * 128 + h * 16];
      floatx4 q0 = qp[0], q1 = qp[1], q2 = qp[2], q3 = qp[3];
      const int t = t0 + t8;
      floatx4 res;
#pragma unroll
      for (int j = 0; j < 4; ++j) {
        floatx4 p = q0 * kr[j * 4 + 0];
        p += q1 * kr[j * 4 + 1];
        p += q2 * kr[j * 4 + 2];
        p += q3 * kr[j * 4 + 3];
        float v = (p[0] + p[1] + p[2] + p[3]) * 0.25f;
        int s = s4 * 4 + j;
        bool inband = (s >= t - LWW) && (s <= t + LWW);
        if (!inband) {
          v = fminf(fmaxf(v, -5.f), 5.f);
          if (m[j] == 0) v = 1e-28f;
        }
        res[j] = v;
      }
      *(floatx4*)&sc[(t8 * 8 + h) * SCP + s4 * 4] = res;
    }
  }
  __syncthreads();  // the only block-wide barrier

  const int wid = tid >> 6, lane = tid & 63;
  const int tw0 = t0 + wid * 2;             // this wave's two rows
  float* scw = &sc[(wid * 2) * 8 * SCP];    // wave's sc slice: [(r*8+h)*SCP+s]

  // ---- Phase B (wave-local): banded edge bias g = tv@Wg+bg; clip+mask ----
  if (lane < 34) {
    const int r = lane / 17, ds = lane - r * 17;
    const int t = tw0 + r, s = t - LWW + ds;
    if (s >= 0 && s < TT) {
      const floatx4* tp =
          (const floatx4*)&tv[(((size_t)(bn * TT + t)) * TT + s) * DEE];
      floatx4 glo = *(const floatx4*)&bg[0];
      floatx4 ghi = *(const floatx4*)&bg[4];
#pragma unroll
      for (int c4 = 0; c4 < 8; ++c4) {
        floatx4 tvv = tp[c4];
#pragma unroll
        for (int k = 0; k < 4; ++k) {
          floatx4 wlo = *(const floatx4*)&Wg[(c4 * 4 + k) * 8];
          floatx4 whi = *(const floatx4*)&Wg[(c4 * 4 + k) * 8 + 4];
          glo += tvv[k] * wlo;
          ghi += tvv[k] * whi;
        }
      }
      int m0 = mask[b * TT + s];
      float* base = &scw[r * 8 * SCP + s];
#pragma unroll
      for (int h = 0; h < 8; ++h) {
        float gv = (h < 4) ? glo[h] : ghi[h - 4];
        float v = base[h * SCP] + gv;
        v = fminf(fmaxf(v, -5.f), 5.f);
        if (m0 == 0) v = 1e-28f;
        base[h * SCP] = v;
      }
    }
  }
  __builtin_amdgcn_wave_barrier();

  // ---- Phase C (wave-local): tv_out = sc @ W_upd + b_upd, NT stores ----
  {
    const int e4 = lane & 7;    // output float4 within DE
    const int sq0 = lane >> 3;  // s-quads sq0, sq0+8, sq0+16, sq0+24
    floatx4 wv[HH];
#pragma unroll
    for (int h = 0; h < HH; ++h) wv[h] = *(const floatx4*)&Wupd[h * 32 + e4 * 4];
    floatx4 bu = *(const floatx4*)&bupd[e4 * 4];
#pragma unroll
    for (int r = 0; r < 2; ++r) {
      const float* scr = &scw[r * 8 * SCP];
      float* op = out1 + ((size_t)(bn * TT + tw0 + r)) * TT * DEE;
#pragma unroll
      for (int si = 0; si < 4; ++si) {
        int sq = sq0 + si * 8;
        floatx4 o0 = bu, o1 = bu, o2 = bu, o3 = bu;
#pragma unroll
        for (int h = 0; h < HH; ++h) {
          floatx4 f = *(const floatx4*)&scr[h * SCP + sq * 4];
          o0 += f[0] * wv[h];
          o1 += f[1] * wv[h];
          o2 += f[2] * wv[h];
          o3 += f[3] * wv[h];
        }
        __builtin_nontemporal_store(o0, (floatx4*)&op[(sq * 4 + 0) * DEE + e4 * 4]);
        __builtin_nontemporal_store(o1, (floatx4*)&op[(sq * 4 + 1) * DEE + e4 * 4]);
        __builtin_nontemporal_store(o2, (floatx4*)&op[(sq * 4 + 2) * DEE + e4 * 4]);
        __builtin_nontemporal_store(o3, (floatx4*)&op[(sq * 4 + 3) * DEE + e4 * 4]);
      }
    }
  }
  __builtin_amdgcn_wave_barrier();

  // ---- Phase D (wave-local): softmax over s per (t,h); 8 lanes per h ----
  {
    const int h = lane >> 3, sp = lane & 7;  // lane's s set: sp*4+{0..3}+32q
    int4 mi0 = *(const int4*)&mask[b * TT + sp * 4];
    int4 mi1 = *(const int4*)&mask[b * TT + sp * 4 + 32];
    int4 mi2 = *(const int4*)&mask[b * TT + sp * 4 + 64];
    int4 mi3 = *(const int4*)&mask[b * TT + sp * 4 + 96];
#pragma unroll
    for (int r = 0; r < 2; ++r) {
      float* rp = &scw[(r * 8 + h) * SCP];
      floatx4 x0 = *(const floatx4*)&rp[sp * 4];
      floatx4 x1 = *(const floatx4*)&rp[sp * 4 + 32];
      floatx4 x2 = *(const floatx4*)&rp[sp * 4 + 64];
      floatx4 x3 = *(const floatx4*)&rp[sp * 4 + 96];
      float m = fmaxf(fmaxf(fmaxf(x0[0], x0[1]), fmaxf(x0[2], x0[3])),
                      fmaxf(fmaxf(x1[0], x1[1]), fmaxf(x1[2], x1[3])));
      m = fmaxf(m, fmaxf(fmaxf(fmaxf(x2[0], x2[1]), fmaxf(x2[2], x2[3])),
                         fmaxf(fmaxf(x3[0], x3[1]), fmaxf(x3[2], x3[3]))));
      m = fmaxf(m, __shfl_xor(m, 1));
      m = fmaxf(m, __shfl_xor(m, 2));
      m = fmaxf(m, __shfl_xor(m, 4));
      floatx4 e0, e1, e2, e3;
#pragma unroll
      for (int j = 0; j < 4; ++j) {
        e0[j] = __expf(x0[j] - m);
        e1[j] = __expf(x1[j] - m);
        e2[j] = __expf(x2[j] - m);
        e3[j] = __expf(x3[j] - m);
      }
      float ssum = (e0[0] + e0[1] + e0[2] + e0[3]) + (e1[0] + e1[1] + e1[2] + e1[3]) +
                   (e2[0] + e2[1] + e2[2] + e2[3]) + (e3[0] + e3[1] + e3[2] + e3[3]);
      ssum += __shfl_xor(ssum, 1);
      ssum += __shfl_xor(ssum, 2);
      ssum += __shfl_xor(ssum, 4);
      float inv = 1.f / ssum;
      floatx4 y0, y1, y2, y3;
      y0[0] = (mi0.x == 0) ? 0.f : e0[0] * inv;
      y0[1] = (mi0.y == 0) ? 0.f : e0[1] * inv;
      y0[2] = (mi0.z == 0) ? 0.f : e0[2] * inv;
      y0[3] = (mi0.w == 0) ? 0.f : e0[3] * inv;
      y1[0] = (mi1.x == 0) ? 0.f : e1[0] * inv;
      y1[1] = (mi1.y == 0) ? 0.f : e1[1] * inv;
      y1[2] = (mi1.z == 0) ? 0.f : e1[2] * inv;
      y1[3] = (mi1.w == 0) ? 0.f : e1[3] * inv;
      y2[0] = (mi2.x == 0) ? 0.f : e2[0] * inv;
      y2[1] = (mi2.y == 0) ? 0.f : e2[1] * inv;
      y2[2] = (mi2.z == 0) ? 0.f : e2[2] * inv;
      y2[3] = (mi2.w == 0) ? 0.f : e2[3] * inv;
      y3[0] = (mi3.x == 0) ? 0.f : e3[0] * inv;
      y3[1] = (mi3.y == 0) ? 0.f : e3[1] * inv;
      y3[2] = (mi3.z == 0) ? 0.f : e3[2] * inv;
      y3[3] = (mi3.w == 0) ? 0.f : e3[3] * inv;
      *(floatx4*)&rp[sp * 4]      = y0;
      *(floatx4*)&rp[sp * 4 + 32] = y1;
      *(floatx4*)&rp[sp * 4 + 64] = y2;
      *(floatx4*)&rp[sp * 4 + 96] = y3;
    }
  }
  __builtin_amdgcn_wave_barrier();

  // ---- Phase E (wave-local): xo = attn @ V; lane = (h, dk2); V read once
  //      per wave (amortized over the wave's 2 rows) ----
  {
    const int h = lane >> 3, dk2 = lane & 7;
    const floatx4* vp0 =
        (const floatx4*)&V[(((size_t)(bn * 8 + h)) * 16 + dk2) * 128];
    const floatx4* vp1 =
        (const floatx4*)&V[(((size_t)(bn * 8 + h)) * 16 + dk2 + 8) * 128];
    const floatx4* ap0 = (const floatx4*)&scw[(0 * 8 + h) * SCP];
    const floatx4* ap1 = (const floatx4*)&scw[(1 * 8 + h) * SCP];
    floatx4 a00 = 0.f, a01 = 0.f, a10 = 0.f, a11 = 0.f;
#pragma unroll 4
    for (int s4 = 0; s4 < 32; ++s4) {
      floatx4 v0 = vp0[s4], v1 = vp1[s4];
      floatx4 p0 = ap0[s4], p1 = ap1[s4];
      a00 += p0 * v0;
      a01 += p0 * v1;
      a10 += p1 * v0;
      a11 += p1 * v1;
    }
    float* xw = &xo[wid][0][0];
    xw[h * 16 + dk2]           = a00[0] + a00[1] + a00[2] + a00[3];
    xw[h * 16 + dk2 + 8]       = a01[0] + a01[1] + a01[2] + a01[3];
    xw[128 + h * 16 + dk2]     = a10[0] + a10[1] + a10[2] + a10[3];
    xw[128 + h * 16 + dk2 + 8] = a11[0] + a11[1] + a11[2] + a11[3];
  }
  __builtin_amdgcn_wave_barrier();

  // ---- Phase F (wave-local): out0 = xo @ W_out + b_out; c split across
  //      wave halves, combined via shfl_xor(.,32); Wout amortized 2 rows ----
  {
    const int d4 = lane & 31, ch = lane >> 5;
    const float* xp0 = &xo[wid][0][0];
    const float* xp1 = &xo[wid][1][0];
    floatx4 acc0 = 0.f, acc1 = 0.f;
#pragma unroll 8
    for (int ci = 0; ci < 64; ++ci) {
      int c = ch * 64 + ci;
      floatx4 w = *(const floatx4*)&Wout[(size_t)c * 128 + d4 * 4];
      acc0 += xp0[c] * w;
      acc1 += xp1[c] * w;
    }
#pragma unroll
    for (int j = 0; j < 4; ++j) {
      acc0[j] += __shfl_xor(acc0[j], 32);
      acc1[j] += __shfl_xor(acc1[j], 32);
    }
    floatx4 bo = *(const floatx4*)&bout[d4 * 4];
    floatx4 res = (ch == 0 ? acc0 : acc1) + bo;
    int t = tw0 + ch;
    __builtin_nontemporal_store(res,
        (floatx4*)&out0[(((size_t)(b * TT + t)) * NN + n) * DD + d4 * 4]);
  }
}

extern "C" void kernel_launch(void* const* d_in, const int* in_sizes, int n_in,
                              void* d_out, int out_size, void* d_ws, size_t ws_size,
                              hipStream_t stream) {
  const float* node = (const float*)d_in[0];
  const float* tv   = (const float*)d_in[1];
  const int*   mask = (const int*)d_in[2];
  // d_in[3] local_mask: banded |i-j|<=LW, synthesized in-kernel
  const float* Wqkv = (const float*)d_in[4];
  const float* bqkv = (const float*)d_in[5];
  const float* Wg   = (const float*)d_in[6];
  const float* bg   = (const float*)d_in[7];
  const float* Wout = (const float*)d_in[8];
  const float* bout = (const float*)d_in[9];
  const float* Wupd = (const float*)d_in[10];
  const float* bupd = (const float*)d_in[11];

  float* out0 = (float*)d_out;                       // (B,T,N,D)
  float* out1 = out0 + (size_t)BB * TT * NN * DD;    // (B,N,T,T,DE)

  float* Q = (float*)d_ws;                           // BN*T*128 each
  float* K = Q + (size_t)BNN * TT * DD;
  float* V = K + (size_t)BNN * TT * DD;

  qkv_kernel<<<256, 256, 0, stream>>>(node, Wqkv, bqkv, Q, K, V);
  attn_kernel<<<2048, 256, 0, stream>>>(Q, K, V, tv, mask, Wg, bg, Wout, bout,
                                        Wupd, bupd, out0, out1);
}